// Round 15
// baseline (409.600 us; speedup 1.0000x reference)
//
#include <hip/hip_runtime.h>

#define NN   100000
#define EE   1600000
constexpr int RR = 8;
constexpr int BBASES = 4;
constexpr int SCAN_CHUNK = 1024;
constexpr int NBLK = (NN + SCAN_CHUNK - 1) / SCAN_CHUNK; // 98
constexpr int NBUK = 98;                                 // coarse buckets (dst>>10)
constexpr int EPB  = 4096;                               // edges per bin_pass1 block
constexpr int P1BLOCKS = (EE + EPB - 1) / EPB;           // 391

typedef __attribute__((ext_vector_type(8))) short short8;
typedef __attribute__((ext_vector_type(4))) float f32x4;
typedef __attribute__((ext_vector_type(4))) unsigned u32x4;

__device__ __forceinline__ unsigned pack2(float x, float y) {
    unsigned xu = __float_as_uint(x);
    unsigned yu = __float_as_uint(y);
    xu = (xu + 0x7fffu + ((xu >> 16) & 1u)) >> 16;
    yu = (yu + 0x7fffu + ((yu >> 16) & 1u)) & 0xffff0000u;
    return xu | yu;
}

__device__ __forceinline__ unsigned short bf16r(float x) {
    unsigned u = __float_as_uint(x);
    return (unsigned short)((u + 0x7fffu + ((u >> 16) & 1u)) >> 16);
}

// async global->LDS 16B: per-lane global src, wave-uniform LDS base (+lane*16 by HW)
__device__ __forceinline__ void async16(const void* g, void* l) {
    __builtin_amdgcn_global_load_lds(
        (const __attribute__((address_space(1))) void*)g,
        (__attribute__((address_space(3))) void*)l, 16, 0, 0);
}

// ---------------- CSR build: count + scan ----------------

__global__ __launch_bounds__(256) void count_kernel(const int* __restrict__ dst,
                                                    int* __restrict__ counts) {
    int e = blockIdx.x * 256 + threadIdx.x;
    if (e < EE) atomicAdd(&counts[dst[e]], 1);
}

__global__ __launch_bounds__(256) void scan1(const int* __restrict__ counts,
                                             int* __restrict__ offsets,
                                             int* __restrict__ totals) {
    __shared__ int lds[256];
    int b = blockIdx.x, tid = threadIdx.x;
    int base = b * SCAN_CHUNK + tid * 4;
    int v0 = (base + 0 < NN) ? counts[base + 0] : 0;
    int v1 = (base + 1 < NN) ? counts[base + 1] : 0;
    int v2 = (base + 2 < NN) ? counts[base + 2] : 0;
    int v3 = (base + 3 < NN) ? counts[base + 3] : 0;
    int s0 = v0, s1 = s0 + v1, s2 = s1 + v2, s3 = s2 + v3;
    lds[tid] = s3;
    __syncthreads();
    for (int d = 1; d < 256; d <<= 1) {
        int x = (tid >= d) ? lds[tid - d] : 0;
        __syncthreads();
        lds[tid] += x;
        __syncthreads();
    }
    int incl = lds[tid];
    int prefix = incl - s3;
    if (base + 0 < NN) offsets[base + 0] = prefix;
    if (base + 1 < NN) offsets[base + 1] = prefix + s0;
    if (base + 2 < NN) offsets[base + 2] = prefix + s1;
    if (base + 3 < NN) offsets[base + 3] = prefix + s2;
    if (tid == 255) totals[b] = lds[255];
}

// parallel chunk-total scan (128 thr) + gcursor init
__global__ __launch_bounds__(128) void scan2(int* __restrict__ totals,
                                             int* __restrict__ offsets,
                                             int* __restrict__ gcursor) {
    __shared__ int s[128];
    int tid = threadIdx.x;
    int v = (tid < NBLK) ? totals[tid] : 0;
    s[tid] = v;
    __syncthreads();
    for (int d = 1; d < 128; d <<= 1) {
        int x = (tid >= d) ? s[tid - d] : 0;
        __syncthreads();
        s[tid] += x;
        __syncthreads();
    }
    int excl = s[tid] - v;
    if (tid < NBLK) {
        totals[tid] = excl;
        gcursor[tid] = excl;
    }
    if (tid == NBLK - 1) offsets[NN] = excl + v;   // == EE
}

__global__ __launch_bounds__(256) void scan3(int* __restrict__ offsets,
                                             const int* __restrict__ totals) {
    int i = blockIdx.x * 256 + threadIdx.x;
    if (i < NN) offsets[i] += totals[i >> 10];
}

// ---------------- edge binning ----------------

__global__ __launch_bounds__(256) void bin_pass1(const int* __restrict__ src,
                                                 const int* __restrict__ dst,
                                                 const int* __restrict__ et,
                                                 int* __restrict__ gcursor,
                                                 unsigned* __restrict__ tmp) {
    __shared__ unsigned stage[EPB];   // 16 KB
    __shared__ int hist[128];
    __shared__ int sc[128];
    __shared__ int lb[128];
    __shared__ int gb[128];
    int tid = threadIdx.x;
    long e0 = (long)blockIdx.x * EPB;
    if (tid < 128) hist[tid] = 0;
    __syncthreads();

    unsigned w[16];
    int bk[16], pos[16];
#pragma unroll
    for (int i = 0; i < 16; ++i) {
        long e = e0 + i * 256 + tid;
        bool valid = e < EE;
        int d = valid ? dst[e] : 0;
        int s = valid ? src[e] : 0;
        int r = valid ? et[e] : 0;
        bk[i] = d >> 10;
        w[i] = (unsigned)s | ((unsigned)r << 17) | ((unsigned)(d & 1023) << 20);
        pos[i] = valid ? atomicAdd(&hist[bk[i]], 1) : -1;
    }
    __syncthreads();
    if (tid < 128) sc[tid] = hist[tid];
    __syncthreads();
    for (int d = 1; d < 128; d <<= 1) {
        int v = 0;
        if (tid < 128 && tid >= d) v = sc[tid - d];
        __syncthreads();
        if (tid < 128) sc[tid] += v;
        __syncthreads();
    }
    if (tid < 128) lb[tid] = sc[tid] - hist[tid];
    if (tid < NBUK && hist[tid] > 0) gb[tid] = atomicAdd(&gcursor[tid], hist[tid]);
    __syncthreads();
    int total = sc[127];
#pragma unroll
    for (int i = 0; i < 16; ++i) {
        if (pos[i] >= 0) stage[lb[bk[i]] + pos[i]] = w[i];
    }
    __syncthreads();
    for (int s = tid; s < total; s += 256) {
        int lo = 0, hi = 127;
#pragma unroll
        for (int it = 0; it < 7; ++it) {
            int mid = (lo + hi + 1) >> 1;
            if (lb[mid] <= s) lo = mid; else hi = mid - 1;
        }
        tmp[gb[lo] + (s - lb[lo])] = stage[s];
    }
}

// pass2: one block per bucket; (node,relation)-sorted placement via 8192-key LDS scan.
__global__ __launch_bounds__(1024) void bin_pass2(const unsigned* __restrict__ tmp,
                                                  const int* __restrict__ offsets,
                                                  int* __restrict__ packed) {
    __shared__ int hist[8192];   // (dl*8 + r) counters -> cursors (32 KB)
    __shared__ int ssum[1024];
    int b = blockIdx.x, tid = threadIdx.x;
    int nb0 = b << 10;
    int nend = nb0 + 1024; if (nend > NN) nend = NN;
    int beg = offsets[nb0], end = offsets[nend];
#pragma unroll
    for (int i = 0; i < 8; ++i) hist[tid * 8 + i] = 0;
    __syncthreads();
    for (int e = beg + tid; e < end; e += 1024) {
        unsigned wv = tmp[e];
        atomicAdd(&hist[(wv >> 17) & 8191], 1);   // key = dl*8 + r (bits 17..29)
    }
    __syncthreads();
    int loc[8];
    int run = 0;
#pragma unroll
    for (int i = 0; i < 8; ++i) { loc[i] = run; run += hist[tid * 8 + i]; }
    ssum[tid] = run;
    __syncthreads();
    for (int d = 1; d < 1024; d <<= 1) {
        int x = (tid >= d) ? ssum[tid - d] : 0;
        __syncthreads();
        ssum[tid] += x;
        __syncthreads();
    }
    int base = (tid > 0) ? ssum[tid - 1] : 0;
#pragma unroll
    for (int i = 0; i < 8; ++i) hist[tid * 8 + i] = base + loc[i];
    __syncthreads();
    for (int e = beg + tid; e < end; e += 1024) {
        unsigned wv = tmp[e];
        int p = beg + atomicAdd(&hist[(wv >> 17) & 8191], 1);
        packed[p] = (int)((wv & 0x1FFFFu) | (((wv >> 17) & 7u) << 20));
    }
}

// ---------------- weight conversions ----------------

__global__ __launch_bounds__(256) void convert_weights(const float* __restrict__ basis0,
                                                       const float* __restrict__ loop0,
                                                       const float* __restrict__ basis1,
                                                       const float* __restrict__ loop1,
                                                       const float* __restrict__ win,
                                                       const float* __restrict__ wout,
                                                       unsigned short* __restrict__ BT0,
                                                       unsigned short* __restrict__ BT1,
                                                       unsigned short* __restrict__ winT,
                                                       unsigned short* __restrict__ woutT) {
    int i = blockIdx.x * 256 + threadIdx.x;
    if (i < 81920) {
        int n = i / 640, k = i % 640;
        BT0[i] = bf16r(k < 512 ? basis0[(size_t)k * 128 + n] : loop0[(size_t)(k - 512) * 128 + n]);
    } else if (i < 163840) {
        int j = i - 81920;
        int n = j / 640, k = j % 640;
        BT1[j] = bf16r(k < 512 ? basis1[(size_t)k * 128 + n] : loop1[(size_t)(k - 512) * 128 + n]);
    } else if (i < 180224) {
        int j = i - 163840;
        int n = j >> 7, k = j & 127;
        winT[j] = bf16r(win[(size_t)k * 128 + n]);
    } else if (i < 188416) {
        int j = i - 180224;
        int n = j >> 7, k = j & 127;
        woutT[j] = bf16r(wout[(size_t)k * 64 + n]);
    }
}

// ---------------- MFMA GEMM, K=128 (input layer) ----------------
template <int NC, bool F32OUT, bool AF32>
__global__ __launch_bounds__(256) void gemm128(const void* __restrict__ Aptr,
                                               const unsigned short* __restrict__ BT,
                                               const float* __restrict__ bias,
                                               void* __restrict__ outp, int M) {
    constexpr int NFRAG = NC / 32;
    constexpr int BQ = NC * 8 / 256;
    __shared__ __align__(16) char As[2][16384];
    __shared__ __align__(16) char Bs[2][NC * 128];
    int tid = threadIdx.x;
    int lane = tid & 63;
    int wave = tid >> 6;
    int wm = wave >> 1, wn = wave & 1;
    int m0 = blockIdx.x * 128;

    uint4 areg[4], breg[BQ];
    auto loadA = [&](int c) {
#pragma unroll
        for (int q = 0; q < 4; ++q) {
            int lin = q * 256 + tid;
            int row = lin >> 3, slot = lin & 7;
            int gr = m0 + row;
            gr = (gr < M) ? gr : (M - 1);
            if (AF32) {
                const float* fp = (const float*)Aptr + (size_t)gr * 128 + c * 64 + slot * 8;
                float4 v0 = *(const float4*)fp;
                float4 v1 = *(const float4*)(fp + 4);
                areg[q].x = pack2(v0.x, v0.y);
                areg[q].y = pack2(v0.z, v0.w);
                areg[q].z = pack2(v1.x, v1.y);
                areg[q].w = pack2(v1.z, v1.w);
            } else {
                areg[q] = *(const uint4*)((const char*)Aptr + (size_t)gr * 256 + c * 128 + slot * 16);
            }
        }
    };
    auto loadB = [&](int c) {
#pragma unroll
        for (int q = 0; q < BQ; ++q) {
            int lin = q * 256 + tid;
            int n = lin >> 3, slot = lin & 7;
            breg[q] = *(const uint4*)((const char*)BT + (size_t)n * 256 + c * 128 + slot * 16);
        }
    };

    f32x4 acc[4][NFRAG];
#pragma unroll
    for (int m = 0; m < 4; ++m)
#pragma unroll
        for (int n = 0; n < NFRAG; ++n) acc[m][n] = (f32x4)0.f;

    loadA(0); loadB(0);
    int swz = (lane & 7) << 4;

    for (int c = 0; c < 2; ++c) {
        int buf = c & 1;
#pragma unroll
        for (int q = 0; q < 4; ++q) {
            int lin = q * 256 + tid;
            int row = lin >> 3, slot = lin & 7;
            *(uint4*)(As[buf] + row * 128 + ((slot * 16) ^ ((row & 7) << 4))) = areg[q];
        }
#pragma unroll
        for (int q = 0; q < BQ; ++q) {
            int lin = q * 256 + tid;
            int row = lin >> 3, slot = lin & 7;
            *(uint4*)(Bs[buf] + row * 128 + ((slot * 16) ^ ((row & 7) << 4))) = breg[q];
        }
        __syncthreads();
        if (c < 1) { loadA(1); loadB(1); }
#pragma unroll
        for (int ks = 0; ks < 2; ++ks) {
            short8 a[4], b[NFRAG];
            int kb = ks * 64 + (lane >> 4) * 16;
#pragma unroll
            for (int m = 0; m < 4; ++m) {
                int row = wm * 64 + m * 16 + (lane & 15);
                a[m] = *(const short8*)(As[buf] + row * 128 + (kb ^ swz));
            }
#pragma unroll
            for (int n = 0; n < NFRAG; ++n) {
                int col = wn * (NC / 2) + n * 16 + (lane & 15);
                b[n] = *(const short8*)(Bs[buf] + col * 128 + (kb ^ swz));
            }
#pragma unroll
            for (int m = 0; m < 4; ++m)
#pragma unroll
                for (int n = 0; n < NFRAG; ++n)
                    acc[m][n] = __builtin_amdgcn_mfma_f32_16x16x32_bf16(a[m], b[n], acc[m][n], 0, 0, 0);
        }
        __syncthreads();
    }

    int colbase = wn * (NC / 2) + (lane & 15);
    float bias_v[NFRAG];
#pragma unroll
    for (int n = 0; n < NFRAG; ++n) bias_v[n] = bias[colbase + n * 16];
#pragma unroll
    for (int m = 0; m < 4; ++m) {
        int rl0 = m0 + wm * 64 + m * 16 + ((lane >> 4) << 2);
#pragma unroll
        for (int n = 0; n < NFRAG; ++n) {
            int col = colbase + n * 16;
#pragma unroll
            for (int q = 0; q < 4; ++q) {
                float v = fmaxf(acc[m][n][q] + bias_v[n], 0.f);
                int row = rl0 + q;
                if (F32OUT) {
                    if (row < M) ((float*)outp)[(size_t)row * NC + col] = v;
                } else {
                    float vo = __shfl_xor(v, 1);
                    if (((lane & 1) == 0) && row < M)
                        ((unsigned*)outp)[(size_t)row * (NC / 2) + (col >> 1)] = pack2(v, vo);
                }
            }
        }
    }
}

// ---------------- aggregation: quarter-wave gather (4 edges / vector instr) ----------------
// 16 lanes x uint4 (16B) = one 256B h-row; the 4 quarters of a wave process 4 nodes.
// Padded steps use r_=8 -> wc[32..35]=0 (zero weight), no mask multiplies.

__global__ __launch_bounds__(256) void agg_kernel(const unsigned* __restrict__ hin, // [N][64] bf16x2
                                                  const int* __restrict__ offsets,
                                                  const int* __restrict__ packed,
                                                  const float* __restrict__ wcomp,  // [8][4]
                                                  unsigned* __restrict__ tbuf,      // [len][256]
                                                  int chunk_start, int chunk_len) {
    __shared__ float wc[64];
    int tid = threadIdx.x;
    if (tid < 64) wc[tid] = (tid < 32) ? wcomp[tid] : 0.f;
    __syncthreads();
    int lane = tid & 63;
    int quad = lane >> 4;        // 0..3 -> node within group
    int l4 = lane & 15;          // 0..15 -> uint4 column
    int base_nl = (blockIdx.x * 4 + (tid >> 6)) * 4;
    if (base_nl >= chunk_len) return;
    int nl = base_nl + quad;
    bool hasN = nl < chunk_len;
    int nc = chunk_start + (hasN ? nl : (chunk_len - 1));
    int ebeg = offsets[nc];
    int eend = offsets[nc + 1];
    if (!hasN) eend = ebeg;
    int deg = eend - ebeg;
    // wave-uniform step count = max degree over the 4 quads
    int m1 = __shfl_xor(deg, 16); int d2 = (deg > m1) ? deg : m1;
    int m2 = __shfl_xor(d2, 32);  int steps = (d2 > m2) ? d2 : m2;
    int elast = eend - 1; if (elast < ebeg) elast = ebeg;   // packed padded by +16 at EE

    const u32x4* hin4 = (const u32x4*)hin;
    float a0[8] = {0.f,0.f,0.f,0.f,0.f,0.f,0.f,0.f};
    float a1[8] = {0.f,0.f,0.f,0.f,0.f,0.f,0.f,0.f};
    float a2[8] = {0.f,0.f,0.f,0.f,0.f,0.f,0.f,0.f};
    float a3[8] = {0.f,0.f,0.f,0.f,0.f,0.f,0.f,0.f};

#define CONS(u, hv, ei)                                                     \
    {                                                                       \
        int r_ = ((ei) < eend) ? (int)((u) >> 20) : 8;                      \
        float x0_ = __uint_as_float((hv).x << 16);                          \
        float x1_ = __uint_as_float((hv).x & 0xffff0000u);                  \
        float x2_ = __uint_as_float((hv).y << 16);                          \
        float x3_ = __uint_as_float((hv).y & 0xffff0000u);                  \
        float x4_ = __uint_as_float((hv).z << 16);                          \
        float x5_ = __uint_as_float((hv).z & 0xffff0000u);                  \
        float x6_ = __uint_as_float((hv).w << 16);                          \
        float x7_ = __uint_as_float((hv).w & 0xffff0000u);                  \
        float w0_ = wc[r_ * 4 + 0], w1_ = wc[r_ * 4 + 1];                   \
        float w2_ = wc[r_ * 4 + 2], w3_ = wc[r_ * 4 + 3];                   \
        a0[0]=fmaf(w0_,x0_,a0[0]); a0[1]=fmaf(w0_,x1_,a0[1]);               \
        a0[2]=fmaf(w0_,x2_,a0[2]); a0[3]=fmaf(w0_,x3_,a0[3]);               \
        a0[4]=fmaf(w0_,x4_,a0[4]); a0[5]=fmaf(w0_,x5_,a0[5]);               \
        a0[6]=fmaf(w0_,x6_,a0[6]); a0[7]=fmaf(w0_,x7_,a0[7]);               \
        a1[0]=fmaf(w1_,x0_,a1[0]); a1[1]=fmaf(w1_,x1_,a1[1]);               \
        a1[2]=fmaf(w1_,x2_,a1[2]); a1[3]=fmaf(w1_,x3_,a1[3]);               \
        a1[4]=fmaf(w1_,x4_,a1[4]); a1[5]=fmaf(w1_,x5_,a1[5]);               \
        a1[6]=fmaf(w1_,x6_,a1[6]); a1[7]=fmaf(w1_,x7_,a1[7]);               \
        a2[0]=fmaf(w2_,x0_,a2[0]); a2[1]=fmaf(w2_,x1_,a2[1]);               \
        a2[2]=fmaf(w2_,x2_,a2[2]); a2[3]=fmaf(w2_,x3_,a2[3]);               \
        a2[4]=fmaf(w2_,x4_,a2[4]); a2[5]=fmaf(w2_,x5_,a2[5]);               \
        a2[6]=fmaf(w2_,x6_,a2[6]); a2[7]=fmaf(w2_,x7_,a2[7]);               \
        a3[0]=fmaf(w3_,x0_,a3[0]); a3[1]=fmaf(w3_,x1_,a3[1]);               \
        a3[2]=fmaf(w3_,x2_,a3[2]); a3[3]=fmaf(w3_,x3_,a3[3]);               \
        a3[4]=fmaf(w3_,x4_,a3[4]); a3[5]=fmaf(w3_,x5_,a3[5]);               \
        a3[6]=fmaf(w3_,x6_,a3[6]); a3[7]=fmaf(w3_,x7_,a3[7]);               \
    }

    int e = ebeg;
    for (int s = 0; s < steps; s += 4) {
        int i0 = e + 0; i0 = (i0 <= elast) ? i0 : elast;
        int i1 = e + 1; i1 = (i1 <= elast) ? i1 : elast;
        int i2 = e + 2; i2 = (i2 <= elast) ? i2 : elast;
        int i3 = e + 3; i3 = (i3 <= elast) ? i3 : elast;
        unsigned u0 = (unsigned)packed[i0];
        unsigned u1 = (unsigned)packed[i1];
        unsigned u2 = (unsigned)packed[i2];
        unsigned u3 = (unsigned)packed[i3];
        u32x4 h0 = hin4[(size_t)(u0 & 0xFFFFFu) * 16 + l4];
        u32x4 h1 = hin4[(size_t)(u1 & 0xFFFFFu) * 16 + l4];
        u32x4 h2 = hin4[(size_t)(u2 & 0xFFFFFu) * 16 + l4];
        u32x4 h3 = hin4[(size_t)(u3 & 0xFFFFFu) * 16 + l4];
        CONS(u0, h0, e + 0);
        CONS(u1, h1, e + 1);
        CONS(u2, h2, e + 2);
        CONS(u3, h3, e + 3);
        e += 4;
    }
#undef CONS

    if (hasN) {
        size_t tb = (size_t)nl * 256 + 4 * l4;
        u32x4 v0, v1, v2, v3;
        v0.x = pack2(a0[0], a0[1]); v0.y = pack2(a0[2], a0[3]);
        v0.z = pack2(a0[4], a0[5]); v0.w = pack2(a0[6], a0[7]);
        v1.x = pack2(a1[0], a1[1]); v1.y = pack2(a1[2], a1[3]);
        v1.z = pack2(a1[4], a1[5]); v1.w = pack2(a1[6], a1[7]);
        v2.x = pack2(a2[0], a2[1]); v2.y = pack2(a2[2], a2[3]);
        v2.z = pack2(a2[4], a2[5]); v2.w = pack2(a2[6], a2[7]);
        v3.x = pack2(a3[0], a3[1]); v3.y = pack2(a3[2], a3[3]);
        v3.z = pack2(a3[4], a3[5]); v3.w = pack2(a3[6], a3[7]);
        __builtin_nontemporal_store(v0, (u32x4*)(tbuf + tb + 0));
        __builtin_nontemporal_store(v1, (u32x4*)(tbuf + tb + 64));
        __builtin_nontemporal_store(v2, (u32x4*)(tbuf + tb + 128));
        __builtin_nontemporal_store(v3, (u32x4*)(tbuf + tb + 192));
    }
}

// ---------------- conv GEMM (+ optional fused output layer) ----------------

template <bool FUSE_OUT>
__global__ __launch_bounds__(256) void conv_gemm(const unsigned* __restrict__ tbuf, // [len][256]
                                                 const unsigned* __restrict__ hin,  // [N][64]
                                                 const unsigned short* __restrict__ BT, // [128][640]
                                                 const float* __restrict__ hbias,   // [128]
                                                 unsigned* __restrict__ hout,       // [N][64]
                                                 const unsigned short* __restrict__ WoutT, // [64][128]
                                                 const float* __restrict__ bout,    // [64]
                                                 float* __restrict__ outp,          // [N][64]
                                                 int chunk_start, int chunk_len) {
    __shared__ __align__(16) char As[2][16384];
    __shared__ __align__(16) char Bs[2][16384];
    __shared__ __align__(16) char Ws[16384];   // woutT tile (FUSE_OUT only)
    int tid = threadIdx.x;
    int lane = tid & 63;
    int wave = tid >> 6;
    int wm = wave >> 1, wn = wave & 1;
    int m0 = blockIdx.x * 128;

    auto stage = [&](int c, int buf) {
#pragma unroll
        for (int q = 0; q < 4; ++q) {
            int row = q * 32 + wave * 8 + (lane >> 3);     // row&7 == lane>>3
            int s_src = (lane & 7) ^ (lane >> 3);          // pre-swizzled source slot
            int lr = m0 + row;
            lr = (lr < chunk_len) ? lr : (chunk_len - 1);
            const char* ga = (c < 8)
                ? (const char*)(tbuf + (size_t)lr * 256) + c * 128 + s_src * 16
                : (const char*)(hin + (size_t)(chunk_start + lr) * 64) + (c - 8) * 128 + s_src * 16;
            async16(ga, &As[buf][q * 4096 + wave * 1024]);
            const char* gb = (const char*)BT + (size_t)row * 1280 + c * 128 + s_src * 16;
            async16(gb, &Bs[buf][q * 4096 + wave * 1024]);
        }
    };

    f32x4 acc[4][4];
#pragma unroll
    for (int m = 0; m < 4; ++m)
#pragma unroll
        for (int n = 0; n < 4; ++n) acc[m][n] = (f32x4)0.f;

    stage(0, 0);
    if (FUSE_OUT) {
#pragma unroll
        for (int q = 0; q < 4; ++q) {
            int row = q * 16 + wave * 4 + (lane >> 4);     // 0..63
            int s_src = (lane & 15) ^ (row & 7);
            async16((const char*)WoutT + (size_t)row * 256 + s_src * 16,
                    &Ws[q * 4096 + wave * 1024]);
        }
    }
    __syncthreads();
    int swz = (lane & 7) << 4;

    for (int c = 0; c < 10; ++c) {
        int buf = c & 1;
        if (c < 9) stage(c + 1, buf ^ 1);
#pragma unroll
        for (int ks = 0; ks < 2; ++ks) {
            short8 a[4], b[4];
            int kb = ks * 64 + (lane >> 4) * 16;
#pragma unroll
            for (int m = 0; m < 4; ++m) {
                int row = wm * 64 + m * 16 + (lane & 15);
                a[m] = *(const short8*)(As[buf] + row * 128 + (kb ^ swz));
            }
#pragma unroll
            for (int n = 0; n < 4; ++n) {
                int col = wn * 64 + n * 16 + (lane & 15);
                b[n] = *(const short8*)(Bs[buf] + col * 128 + (kb ^ swz));
            }
#pragma unroll
            for (int m = 0; m < 4; ++m)
#pragma unroll
                for (int n = 0; n < 4; ++n)
                    acc[m][n] = __builtin_amdgcn_mfma_f32_16x16x32_bf16(a[m], b[n], acc[m][n], 0, 0, 0);
        }
        __syncthreads();
    }

    unsigned* olds = (unsigned*)&As[0][0];   // [128 rows][64 dwords] = 32 KB
    int colbase = wn * 64 + (lane & 15);
    float bias_v[4];
#pragma unroll
    for (int n = 0; n < 4; ++n) bias_v[n] = hbias[colbase + n * 16];

    if (!FUSE_OUT) {
#pragma unroll
        for (int m = 0; m < 4; ++m) {
            int rbase = wm * 64 + m * 16 + ((lane >> 4) << 2);
#pragma unroll
            for (int n = 0; n < 4; ++n) {
#pragma unroll
                for (int q = 0; q < 4; ++q) {
                    float v = fmaxf(acc[m][n][q] + bias_v[n], 0.f);
                    float vo = __shfl_xor(v, 1);
                    if ((lane & 1) == 0) {
                        olds[(rbase + q) * 64 + wn * 32 + n * 8 + ((lane & 15) >> 1)] = pack2(v, vo);
                    }
                }
            }
        }
        __syncthreads();
#pragma unroll
        for (int i = 0; i < 8; ++i) {
            int j = i * 256 + tid;            // uint4 index over [128][16]
            int row = j >> 4, s = j & 15;
            int gr = m0 + row;
            if (gr < chunk_len) {
                ((uint4*)(hout + (size_t)(chunk_start + gr) * 64))[s] = ((const uint4*)olds)[j];
            }
        }
    } else {
        // write h1 to LDS with XOR swizzle (dword d ^= (row&7)<<2)
#pragma unroll
        for (int m = 0; m < 4; ++m) {
            int rbase = wm * 64 + m * 16 + ((lane >> 4) << 2);
#pragma unroll
            for (int n = 0; n < 4; ++n) {
#pragma unroll
                for (int q = 0; q < 4; ++q) {
                    float v = fmaxf(acc[m][n][q] + bias_v[n], 0.f);
                    float vo = __shfl_xor(v, 1);
                    if ((lane & 1) == 0) {
                        int row = rbase + q;
                        int d = wn * 32 + n * 8 + ((lane & 15) >> 1);
                        olds[row * 64 + (d ^ ((row & 7) << 2))] = pack2(v, vo);
                    }
                }
            }
        }
        __syncthreads();
        // mini-GEMM: out = relu(h1[128x128] @ WoutT^T[64x128] + bout), f32
        f32x4 acc2[4][2];
#pragma unroll
        for (int m = 0; m < 4; ++m)
#pragma unroll
            for (int n = 0; n < 2; ++n) acc2[m][n] = (f32x4)0.f;
#pragma unroll
        for (int ks = 0; ks < 4; ++ks) {
            int kb = ks * 64 + (lane >> 4) * 16;
            short8 a2[4], b2[2];
#pragma unroll
            for (int m = 0; m < 4; ++m) {
                int row = wm * 64 + m * 16 + (lane & 15);
                a2[m] = *(const short8*)((const char*)olds + row * 256 + (kb ^ ((row & 7) << 4)));
            }
#pragma unroll
            for (int n = 0; n < 2; ++n) {
                int col = wn * 32 + n * 16 + (lane & 15);
                b2[n] = *(const short8*)(Ws + col * 256 + (kb ^ ((col & 7) << 4)));
            }
#pragma unroll
            for (int m = 0; m < 4; ++m)
#pragma unroll
                for (int n = 0; n < 2; ++n)
                    acc2[m][n] = __builtin_amdgcn_mfma_f32_16x16x32_bf16(a2[m], b2[n], acc2[m][n], 0, 0, 0);
        }
        int colb = wn * 32 + (lane & 15);
        float bv2[2];
#pragma unroll
        for (int n = 0; n < 2; ++n) bv2[n] = bout[colb + n * 16];
#pragma unroll
        for (int m = 0; m < 4; ++m) {
            int rl0 = wm * 64 + m * 16 + ((lane >> 4) << 2);
#pragma unroll
            for (int n = 0; n < 2; ++n) {
#pragma unroll
                for (int q = 0; q < 4; ++q) {
                    int row = rl0 + q;
                    if (m0 + row < chunk_len) {
                        float v = fmaxf(acc2[m][n][q] + bv2[n], 0.f);
                        outp[(size_t)(chunk_start + m0 + row) * 64 + colb + n * 16] = v;
                    }
                }
            }
        }
    }
}

// ---------------- launch ----------------

static inline size_t align256(size_t x) { return (x + 255) & ~(size_t)255; }

extern "C" void kernel_launch(void* const* d_in, const int* in_sizes, int n_in,
                              void* d_out, int out_size, void* d_ws, size_t ws_size,
                              hipStream_t stream) {
    const float* feat   = (const float*)d_in[0];
    const float* win    = (const float*)d_in[1];
    const float* bin_   = (const float*)d_in[2];
    const float* basis0 = (const float*)d_in[3];
    const float* wcomp0 = (const float*)d_in[4];
    const float* loop0  = (const float*)d_in[5];
    const float* hbias0 = (const float*)d_in[6];
    const float* basis1 = (const float*)d_in[7];
    const float* wcomp1 = (const float*)d_in[8];
    const float* loop1  = (const float*)d_in[9];
    const float* hbias1 = (const float*)d_in[10];
    const float* wout   = (const float*)d_in[11];
    const float* bout   = (const float*)d_in[12];
    const int*   src    = (const int*)d_in[13];
    const int*   dst    = (const int*)d_in[14];
    const int*   etyp   = (const int*)d_in[15];
    float* outp = (float*)d_out;

    size_t off = 0;
    char* wsb = (char*)d_ws;
    auto walloc = [&](size_t bytes) { void* p = wsb + off; off += align256(bytes); return p; };
    unsigned* hA  = (unsigned*)walloc((size_t)NN * 64 * 4);     // 25.6 MB
    unsigned* hB  = (unsigned*)walloc((size_t)NN * 64 * 4);     // 25.6 MB
    int* offsets  = (int*)walloc((size_t)(NN + 1) * 4);
    int* counts   = (int*)walloc((size_t)NN * 4);
    int* totals   = (int*)walloc((size_t)NBLK * 4);
    int* gcursor  = (int*)walloc((size_t)NBUK * 4);
    int* packed   = (int*)walloc((size_t)(EE + 16) * 4);        // +pad for clamp overrun
    unsigned* tmp = (unsigned*)walloc((size_t)EE * 4);          // 6.4 MB
    unsigned short* BT0 = (unsigned short*)walloc((size_t)128 * 640 * 2);
    unsigned short* BT1 = (unsigned short*)walloc((size_t)128 * 640 * 2);
    unsigned short* winT = (unsigned short*)walloc((size_t)128 * 128 * 2);
    unsigned short* woutT = (unsigned short*)walloc((size_t)64 * 128 * 2);
    size_t fixed = off;

    int nchunk = 1;
    while (nchunk < 32) {
        size_t rows = (size_t)(NN + nchunk - 1) / nchunk;
        if (fixed + rows * 1024 <= ws_size) break;
        nchunk *= 2;
    }
    int chunk_rows = (NN + nchunk - 1) / nchunk;
    unsigned* tbuf = (unsigned*)(wsb + fixed);

    // CSR build
    hipMemsetAsync(counts, 0, (size_t)NN * 4, stream);
    hipMemsetAsync(packed + EE, 0, 16 * 4, stream);   // guard pad (deg-0 tail clamp)
    count_kernel<<<(EE + 255) / 256, 256, 0, stream>>>(dst, counts);
    scan1<<<NBLK, 256, 0, stream>>>(counts, offsets, totals);
    scan2<<<1, 128, 0, stream>>>(totals, offsets, gcursor);
    scan3<<<(NN + 255) / 256, 256, 0, stream>>>(offsets, totals);
    bin_pass1<<<P1BLOCKS, 256, 0, stream>>>(src, dst, etyp, gcursor, tmp);
    bin_pass2<<<NBUK, 1024, 0, stream>>>(tmp, offsets, packed);

    // weight conversions
    convert_weights<<<(188416 + 255) / 256, 256, 0, stream>>>(
        basis0, loop0, basis1, loop1, win, wout, BT0, BT1, winT, woutT);

    int gblocks = (NN + 127) / 128;  // 782
    // input layer (MFMA, f32 A converted in staging)
    gemm128<128, false, true><<<gblocks, 256, 0, stream>>>(feat, winT, bin_, hA, NN);

    // conv layer 0: hA -> hB
    for (int s = 0; s < NN; s += chunk_rows) {
        int len = (NN - s < chunk_rows) ? (NN - s) : chunk_rows;
        int ngroups = (len + 3) / 4;              // 4 nodes per wave
        agg_kernel<<<(ngroups + 3) / 4, 256, 0, stream>>>(hA, offsets, packed, wcomp0, tbuf, s, len);
        conv_gemm<false><<<(len + 127) / 128, 256, 0, stream>>>(
            tbuf, hA, BT0, hbias0, hB, nullptr, nullptr, nullptr, s, len);
    }
    // conv layer 1 + fused output layer: hB -> out
    for (int s = 0; s < NN; s += chunk_rows) {
        int len = (NN - s < chunk_rows) ? (NN - s) : chunk_rows;
        int ngroups = (len + 3) / 4;
        agg_kernel<<<(ngroups + 3) / 4, 256, 0, stream>>>(hB, offsets, packed, wcomp1, tbuf, s, len);
        conv_gemm<true><<<(len + 127) / 128, 256, 0, stream>>>(
            tbuf, hB, BT1, hbias1, nullptr, woutT, bout, outp, s, len);
    }
}

// Round 16
// 394.613 us; speedup vs baseline: 1.0380x; 1.0380x over previous
//
#include <hip/hip_runtime.h>

#define NN   100000
#define EE   1600000
constexpr int RR = 8;
constexpr int BBASES = 4;
constexpr int SCAN_CHUNK = 1024;
constexpr int NBLK = (NN + SCAN_CHUNK - 1) / SCAN_CHUNK; // 98
constexpr int NBUK = 98;                                 // coarse buckets (dst>>10)
constexpr int EPB  = 4096;                               // edges per bin_pass1 block
constexpr int P1BLOCKS = (EE + EPB - 1) / EPB;           // 391

typedef __attribute__((ext_vector_type(8))) short short8;
typedef __attribute__((ext_vector_type(4))) float f32x4;

__device__ __forceinline__ unsigned pack2(float x, float y) {
    unsigned xu = __float_as_uint(x);
    unsigned yu = __float_as_uint(y);
    xu = (xu + 0x7fffu + ((xu >> 16) & 1u)) >> 16;
    yu = (yu + 0x7fffu + ((yu >> 16) & 1u)) & 0xffff0000u;
    return xu | yu;
}

__device__ __forceinline__ unsigned short bf16r(float x) {
    unsigned u = __float_as_uint(x);
    return (unsigned short)((u + 0x7fffu + ((u >> 16) & 1u)) >> 16);
}

// async global->LDS 16B: per-lane global src, wave-uniform LDS base (+lane*16 by HW)
__device__ __forceinline__ void async16(const void* g, void* l) {
    __builtin_amdgcn_global_load_lds(
        (const __attribute__((address_space(1))) void*)g,
        (__attribute__((address_space(3))) void*)l, 16, 0, 0);
}

// ---------------- CSR build: count + scan ----------------

__global__ __launch_bounds__(256) void count_kernel(const int* __restrict__ dst,
                                                    int* __restrict__ counts) {
    int e = blockIdx.x * 256 + threadIdx.x;
    if (e < EE) atomicAdd(&counts[dst[e]], 1);
}

__global__ __launch_bounds__(256) void scan1(const int* __restrict__ counts,
                                             int* __restrict__ offsets,
                                             int* __restrict__ totals) {
    __shared__ int lds[256];
    int b = blockIdx.x, tid = threadIdx.x;
    int base = b * SCAN_CHUNK + tid * 4;
    int v0 = (base + 0 < NN) ? counts[base + 0] : 0;
    int v1 = (base + 1 < NN) ? counts[base + 1] : 0;
    int v2 = (base + 2 < NN) ? counts[base + 2] : 0;
    int v3 = (base + 3 < NN) ? counts[base + 3] : 0;
    int s0 = v0, s1 = s0 + v1, s2 = s1 + v2, s3 = s2 + v3;
    lds[tid] = s3;
    __syncthreads();
    for (int d = 1; d < 256; d <<= 1) {
        int x = (tid >= d) ? lds[tid - d] : 0;
        __syncthreads();
        lds[tid] += x;
        __syncthreads();
    }
    int incl = lds[tid];
    int prefix = incl - s3;
    if (base + 0 < NN) offsets[base + 0] = prefix;
    if (base + 1 < NN) offsets[base + 1] = prefix + s0;
    if (base + 2 < NN) offsets[base + 2] = prefix + s1;
    if (base + 3 < NN) offsets[base + 3] = prefix + s2;
    if (tid == 255) totals[b] = lds[255];
}

// parallel chunk-total scan (128 thr) + gcursor init
__global__ __launch_bounds__(128) void scan2(int* __restrict__ totals,
                                             int* __restrict__ offsets,
                                             int* __restrict__ gcursor) {
    __shared__ int s[128];
    int tid = threadIdx.x;
    int v = (tid < NBLK) ? totals[tid] : 0;
    s[tid] = v;
    __syncthreads();
    for (int d = 1; d < 128; d <<= 1) {
        int x = (tid >= d) ? s[tid - d] : 0;
        __syncthreads();
        s[tid] += x;
        __syncthreads();
    }
    int excl = s[tid] - v;
    if (tid < NBLK) {
        totals[tid] = excl;
        gcursor[tid] = excl;
    }
    if (tid == NBLK - 1) offsets[NN] = excl + v;   // == EE
}

__global__ __launch_bounds__(256) void scan3(int* __restrict__ offsets,
                                             const int* __restrict__ totals) {
    int i = blockIdx.x * 256 + threadIdx.x;
    if (i < NN) offsets[i] += totals[i >> 10];
}

// ---------------- edge binning ----------------

__global__ __launch_bounds__(256) void bin_pass1(const int* __restrict__ src,
                                                 const int* __restrict__ dst,
                                                 const int* __restrict__ et,
                                                 int* __restrict__ gcursor,
                                                 unsigned* __restrict__ tmp) {
    __shared__ unsigned stage[EPB];   // 16 KB
    __shared__ int hist[128];
    __shared__ int sc[128];
    __shared__ int lb[128];
    __shared__ int gb[128];
    int tid = threadIdx.x;
    long e0 = (long)blockIdx.x * EPB;
    if (tid < 128) hist[tid] = 0;
    __syncthreads();

    unsigned w[16];
    int bk[16], pos[16];
#pragma unroll
    for (int i = 0; i < 16; ++i) {
        long e = e0 + i * 256 + tid;
        bool valid = e < EE;
        int d = valid ? dst[e] : 0;
        int s = valid ? src[e] : 0;
        int r = valid ? et[e] : 0;
        bk[i] = d >> 10;
        w[i] = (unsigned)s | ((unsigned)r << 17) | ((unsigned)(d & 1023) << 20);
        pos[i] = valid ? atomicAdd(&hist[bk[i]], 1) : -1;
    }
    __syncthreads();
    if (tid < 128) sc[tid] = hist[tid];
    __syncthreads();
    for (int d = 1; d < 128; d <<= 1) {
        int v = 0;
        if (tid < 128 && tid >= d) v = sc[tid - d];
        __syncthreads();
        if (tid < 128) sc[tid] += v;
        __syncthreads();
    }
    if (tid < 128) lb[tid] = sc[tid] - hist[tid];
    if (tid < NBUK && hist[tid] > 0) gb[tid] = atomicAdd(&gcursor[tid], hist[tid]);
    __syncthreads();
    int total = sc[127];
#pragma unroll
    for (int i = 0; i < 16; ++i) {
        if (pos[i] >= 0) stage[lb[bk[i]] + pos[i]] = w[i];
    }
    __syncthreads();
    for (int s = tid; s < total; s += 256) {
        int lo = 0, hi = 127;
#pragma unroll
        for (int it = 0; it < 7; ++it) {
            int mid = (lo + hi + 1) >> 1;
            if (lb[mid] <= s) lo = mid; else hi = mid - 1;
        }
        tmp[gb[lo] + (s - lb[lo])] = stage[s];
    }
}

// pass2: one block per bucket; (node,relation)-sorted placement via 8192-key LDS scan.
__global__ __launch_bounds__(1024) void bin_pass2(const unsigned* __restrict__ tmp,
                                                  const int* __restrict__ offsets,
                                                  int* __restrict__ packed) {
    __shared__ int hist[8192];   // (dl*8 + r) counters -> cursors (32 KB)
    __shared__ int ssum[1024];
    int b = blockIdx.x, tid = threadIdx.x;
    int nb0 = b << 10;
    int nend = nb0 + 1024; if (nend > NN) nend = NN;
    int beg = offsets[nb0], end = offsets[nend];
#pragma unroll
    for (int i = 0; i < 8; ++i) hist[tid * 8 + i] = 0;
    __syncthreads();
    for (int e = beg + tid; e < end; e += 1024) {
        unsigned wv = tmp[e];
        atomicAdd(&hist[(wv >> 17) & 8191], 1);   // key = dl*8 + r (bits 17..29)
    }
    __syncthreads();
    int loc[8];
    int run = 0;
#pragma unroll
    for (int i = 0; i < 8; ++i) { loc[i] = run; run += hist[tid * 8 + i]; }
    ssum[tid] = run;
    __syncthreads();
    for (int d = 1; d < 1024; d <<= 1) {
        int x = (tid >= d) ? ssum[tid - d] : 0;
        __syncthreads();
        ssum[tid] += x;
        __syncthreads();
    }
    int base = (tid > 0) ? ssum[tid - 1] : 0;
#pragma unroll
    for (int i = 0; i < 8; ++i) hist[tid * 8 + i] = base + loc[i];
    __syncthreads();
    for (int e = beg + tid; e < end; e += 1024) {
        unsigned wv = tmp[e];
        int p = beg + atomicAdd(&hist[(wv >> 17) & 8191], 1);
        packed[p] = (int)((wv & 0x1FFFFu) | (((wv >> 17) & 7u) << 20));
    }
}

// ---------------- weight conversions ----------------

__global__ __launch_bounds__(256) void convert_weights(const float* __restrict__ basis0,
                                                       const float* __restrict__ loop0,
                                                       const float* __restrict__ basis1,
                                                       const float* __restrict__ loop1,
                                                       const float* __restrict__ win,
                                                       const float* __restrict__ wout,
                                                       unsigned short* __restrict__ BT0,
                                                       unsigned short* __restrict__ BT1,
                                                       unsigned short* __restrict__ winT,
                                                       unsigned short* __restrict__ woutT) {
    int i = blockIdx.x * 256 + threadIdx.x;
    if (i < 81920) {
        int n = i / 640, k = i % 640;
        BT0[i] = bf16r(k < 512 ? basis0[(size_t)k * 128 + n] : loop0[(size_t)(k - 512) * 128 + n]);
    } else if (i < 163840) {
        int j = i - 81920;
        int n = j / 640, k = j % 640;
        BT1[j] = bf16r(k < 512 ? basis1[(size_t)k * 128 + n] : loop1[(size_t)(k - 512) * 128 + n]);
    } else if (i < 180224) {
        int j = i - 163840;
        int n = j >> 7, k = j & 127;
        winT[j] = bf16r(win[(size_t)k * 128 + n]);
    } else if (i < 188416) {
        int j = i - 180224;
        int n = j >> 7, k = j & 127;
        woutT[j] = bf16r(wout[(size_t)k * 64 + n]);
    }
}

// ---------------- MFMA GEMM, K=128 (input layer) ----------------
template <int NC, bool F32OUT, bool AF32>
__global__ __launch_bounds__(256) void gemm128(const void* __restrict__ Aptr,
                                               const unsigned short* __restrict__ BT,
                                               const float* __restrict__ bias,
                                               void* __restrict__ outp, int M) {
    constexpr int NFRAG = NC / 32;
    constexpr int BQ = NC * 8 / 256;
    __shared__ __align__(16) char As[2][16384];
    __shared__ __align__(16) char Bs[2][NC * 128];
    int tid = threadIdx.x;
    int lane = tid & 63;
    int wave = tid >> 6;
    int wm = wave >> 1, wn = wave & 1;
    int m0 = blockIdx.x * 128;

    uint4 areg[4], breg[BQ];
    auto loadA = [&](int c) {
#pragma unroll
        for (int q = 0; q < 4; ++q) {
            int lin = q * 256 + tid;
            int row = lin >> 3, slot = lin & 7;
            int gr = m0 + row;
            gr = (gr < M) ? gr : (M - 1);
            if (AF32) {
                const float* fp = (const float*)Aptr + (size_t)gr * 128 + c * 64 + slot * 8;
                float4 v0 = *(const float4*)fp;
                float4 v1 = *(const float4*)(fp + 4);
                areg[q].x = pack2(v0.x, v0.y);
                areg[q].y = pack2(v0.z, v0.w);
                areg[q].z = pack2(v1.x, v1.y);
                areg[q].w = pack2(v1.z, v1.w);
            } else {
                areg[q] = *(const uint4*)((const char*)Aptr + (size_t)gr * 256 + c * 128 + slot * 16);
            }
        }
    };
    auto loadB = [&](int c) {
#pragma unroll
        for (int q = 0; q < BQ; ++q) {
            int lin = q * 256 + tid;
            int n = lin >> 3, slot = lin & 7;
            breg[q] = *(const uint4*)((const char*)BT + (size_t)n * 256 + c * 128 + slot * 16);
        }
    };

    f32x4 acc[4][NFRAG];
#pragma unroll
    for (int m = 0; m < 4; ++m)
#pragma unroll
        for (int n = 0; n < NFRAG; ++n) acc[m][n] = (f32x4)0.f;

    loadA(0); loadB(0);
    int swz = (lane & 7) << 4;

    for (int c = 0; c < 2; ++c) {
        int buf = c & 1;
#pragma unroll
        for (int q = 0; q < 4; ++q) {
            int lin = q * 256 + tid;
            int row = lin >> 3, slot = lin & 7;
            *(uint4*)(As[buf] + row * 128 + ((slot * 16) ^ ((row & 7) << 4))) = areg[q];
        }
#pragma unroll
        for (int q = 0; q < BQ; ++q) {
            int lin = q * 256 + tid;
            int row = lin >> 3, slot = lin & 7;
            *(uint4*)(Bs[buf] + row * 128 + ((slot * 16) ^ ((row & 7) << 4))) = breg[q];
        }
        __syncthreads();
        if (c < 1) { loadA(1); loadB(1); }
#pragma unroll
        for (int ks = 0; ks < 2; ++ks) {
            short8 a[4], b[NFRAG];
            int kb = ks * 64 + (lane >> 4) * 16;
#pragma unroll
            for (int m = 0; m < 4; ++m) {
                int row = wm * 64 + m * 16 + (lane & 15);
                a[m] = *(const short8*)(As[buf] + row * 128 + (kb ^ swz));
            }
#pragma unroll
            for (int n = 0; n < NFRAG; ++n) {
                int col = wn * (NC / 2) + n * 16 + (lane & 15);
                b[n] = *(const short8*)(Bs[buf] + col * 128 + (kb ^ swz));
            }
#pragma unroll
            for (int m = 0; m < 4; ++m)
#pragma unroll
                for (int n = 0; n < NFRAG; ++n)
                    acc[m][n] = __builtin_amdgcn_mfma_f32_16x16x32_bf16(a[m], b[n], acc[m][n], 0, 0, 0);
        }
        __syncthreads();
    }

    int colbase = wn * (NC / 2) + (lane & 15);
    float bias_v[NFRAG];
#pragma unroll
    for (int n = 0; n < NFRAG; ++n) bias_v[n] = bias[colbase + n * 16];
#pragma unroll
    for (int m = 0; m < 4; ++m) {
        int rl0 = m0 + wm * 64 + m * 16 + ((lane >> 4) << 2);
#pragma unroll
        for (int n = 0; n < NFRAG; ++n) {
            int col = colbase + n * 16;
#pragma unroll
            for (int q = 0; q < 4; ++q) {
                float v = fmaxf(acc[m][n][q] + bias_v[n], 0.f);
                int row = rl0 + q;
                if (F32OUT) {
                    if (row < M) ((float*)outp)[(size_t)row * NC + col] = v;
                } else {
                    float vo = __shfl_xor(v, 1);
                    if (((lane & 1) == 0) && row < M)
                        ((unsigned*)outp)[(size_t)row * (NC / 2) + (col >> 1)] = pack2(v, vo);
                }
            }
        }
    }
}

// ---------------- aggregation: half-wave paired gather (round-13 proven, 395.5us total) ----------------
// Lanes 0..31 process node A (uint2 = 8B/lane of its h-row), lanes 32..63 node B.
// One gather instruction covers one edge of A AND one edge of B.

__global__ __launch_bounds__(256) void agg_kernel(const unsigned* __restrict__ hin, // [N][64] bf16x2
                                                  const int* __restrict__ offsets,
                                                  const int* __restrict__ packed,
                                                  const float* __restrict__ wcomp,  // [8][4]
                                                  unsigned* __restrict__ tbuf,      // [len][256]
                                                  int chunk_start, int chunk_len) {
    __shared__ float wc[32];
    int tid = threadIdx.x;
    if (tid < 32) wc[tid] = wcomp[tid];
    __syncthreads();
    int lane = tid & 63;
    int half = lane >> 5;
    int l5 = lane & 31;
    int pairI = blockIdx.x * 4 + (tid >> 6);
    int nlA = pairI * 2;
    if (nlA >= chunk_len) return;
    bool hasB = (nlA + 1) < chunk_len;
    int nA = chunk_start + nlA;
    int begA = offsets[nA];
    int endA = offsets[nA + 1];
    int endB = hasB ? offsets[nA + 2] : endA;

    int ebeg = half ? endA : begA;   // node B starts at endA (CSR-adjacent)
    int eend = half ? endB : endA;
    const uint2* hin2 = (const uint2*)hin;

    float acc[4][4];
#pragma unroll
    for (int b = 0; b < 4; ++b)
#pragma unroll
        for (int k = 0; k < 4; ++k) acc[b][k] = 0.f;

    int degA = endA - begA;
    int degB = endB - endA;
    int steps = (degA > degB) ? degA : degB;
    int elast = eend - 1; if (elast < 0) elast = 0;

    int e = ebeg;
    for (int s = 0; s < steps; s += 4) {
        int i0 = e + 0; i0 = (i0 <= elast) ? i0 : elast;
        int i1 = e + 1; i1 = (i1 <= elast) ? i1 : elast;
        int i2 = e + 2; i2 = (i2 <= elast) ? i2 : elast;
        int i3 = e + 3; i3 = (i3 <= elast) ? i3 : elast;
        unsigned u0 = (unsigned)packed[i0];
        unsigned u1 = (unsigned)packed[i1];
        unsigned u2 = (unsigned)packed[i2];
        unsigned u3 = (unsigned)packed[i3];
        uint2 h0 = hin2[(size_t)(u0 & 0xFFFFFu) * 32 + l5];
        uint2 h1 = hin2[(size_t)(u1 & 0xFFFFFu) * 32 + l5];
        uint2 h2 = hin2[(size_t)(u2 & 0xFFFFFu) * 32 + l5];
        uint2 h3 = hin2[(size_t)(u3 & 0xFFFFFu) * 32 + l5];
#define CONS(u, hv, ei)                                                     \
        {                                                                   \
            float m_ = ((ei) < eend) ? 1.f : 0.f;                           \
            int r_ = (int)((u) >> 20);                                      \
            float x0_ = __uint_as_float((hv).x << 16) * m_;                 \
            float y0_ = __uint_as_float((hv).x & 0xffff0000u) * m_;         \
            float x1_ = __uint_as_float((hv).y << 16) * m_;                 \
            float y1_ = __uint_as_float((hv).y & 0xffff0000u) * m_;         \
            _Pragma("unroll")                                               \
            for (int b = 0; b < 4; ++b) {                                   \
                float w_ = wc[r_ * 4 + b];                                  \
                acc[b][0] = fmaf(w_, x0_, acc[b][0]);                       \
                acc[b][1] = fmaf(w_, y0_, acc[b][1]);                       \
                acc[b][2] = fmaf(w_, x1_, acc[b][2]);                       \
                acc[b][3] = fmaf(w_, y1_, acc[b][3]);                       \
            }                                                               \
        }
        CONS(u0, h0, e + 0);
        CONS(u1, h1, e + 1);
        CONS(u2, h2, e + 2);
        CONS(u3, h3, e + 3);
#undef CONS
        e += 4;
    }

    int nlX = nlA + half;
    if (half == 0 || hasB) {
        size_t tb = (size_t)nlX * 256 + 2 * l5;
#pragma unroll
        for (int b = 0; b < 4; ++b) {
            uint2 v;
            v.x = pack2(acc[b][0], acc[b][1]);
            v.y = pack2(acc[b][2], acc[b][3]);
            *(uint2*)(tbuf + tb + b * 64) = v;
        }
    }
}

// ---------------- conv GEMM (+ optional fused output layer) ----------------

template <bool FUSE_OUT>
__global__ __launch_bounds__(256) void conv_gemm(const unsigned* __restrict__ tbuf, // [len][256]
                                                 const unsigned* __restrict__ hin,  // [N][64]
                                                 const unsigned short* __restrict__ BT, // [128][640]
                                                 const float* __restrict__ hbias,   // [128]
                                                 unsigned* __restrict__ hout,       // [N][64]
                                                 const unsigned short* __restrict__ WoutT, // [64][128]
                                                 const float* __restrict__ bout,    // [64]
                                                 float* __restrict__ outp,          // [N][64]
                                                 int chunk_start, int chunk_len) {
    __shared__ __align__(16) char As[2][16384];
    __shared__ __align__(16) char Bs[2][16384];
    __shared__ __align__(16) char Ws[16384];   // woutT tile (FUSE_OUT only)
    int tid = threadIdx.x;
    int lane = tid & 63;
    int wave = tid >> 6;
    int wm = wave >> 1, wn = wave & 1;
    int m0 = blockIdx.x * 128;

    auto stage = [&](int c, int buf) {
#pragma unroll
        for (int q = 0; q < 4; ++q) {
            int row = q * 32 + wave * 8 + (lane >> 3);     // row&7 == lane>>3
            int s_src = (lane & 7) ^ (lane >> 3);          // pre-swizzled source slot
            int lr = m0 + row;
            lr = (lr < chunk_len) ? lr : (chunk_len - 1);
            const char* ga = (c < 8)
                ? (const char*)(tbuf + (size_t)lr * 256) + c * 128 + s_src * 16
                : (const char*)(hin + (size_t)(chunk_start + lr) * 64) + (c - 8) * 128 + s_src * 16;
            async16(ga, &As[buf][q * 4096 + wave * 1024]);
            const char* gb = (const char*)BT + (size_t)row * 1280 + c * 128 + s_src * 16;
            async16(gb, &Bs[buf][q * 4096 + wave * 1024]);
        }
    };

    f32x4 acc[4][4];
#pragma unroll
    for (int m = 0; m < 4; ++m)
#pragma unroll
        for (int n = 0; n < 4; ++n) acc[m][n] = (f32x4)0.f;

    stage(0, 0);
    if (FUSE_OUT) {
#pragma unroll
        for (int q = 0; q < 4; ++q) {
            int row = q * 16 + wave * 4 + (lane >> 4);     // 0..63
            int s_src = (lane & 15) ^ (row & 7);
            async16((const char*)WoutT + (size_t)row * 256 + s_src * 16,
                    &Ws[q * 4096 + wave * 1024]);
        }
    }
    __syncthreads();
    int swz = (lane & 7) << 4;

    for (int c = 0; c < 10; ++c) {
        int buf = c & 1;
        if (c < 9) stage(c + 1, buf ^ 1);
#pragma unroll
        for (int ks = 0; ks < 2; ++ks) {
            short8 a[4], b[4];
            int kb = ks * 64 + (lane >> 4) * 16;
#pragma unroll
            for (int m = 0; m < 4; ++m) {
                int row = wm * 64 + m * 16 + (lane & 15);
                a[m] = *(const short8*)(As[buf] + row * 128 + (kb ^ swz));
            }
#pragma unroll
            for (int n = 0; n < 4; ++n) {
                int col = wn * 64 + n * 16 + (lane & 15);
                b[n] = *(const short8*)(Bs[buf] + col * 128 + (kb ^ swz));
            }
#pragma unroll
            for (int m = 0; m < 4; ++m)
#pragma unroll
                for (int n = 0; n < 4; ++n)
                    acc[m][n] = __builtin_amdgcn_mfma_f32_16x16x32_bf16(a[m], b[n], acc[m][n], 0, 0, 0);
        }
        __syncthreads();
    }

    unsigned* olds = (unsigned*)&As[0][0];   // [128 rows][64 dwords] = 32 KB
    int colbase = wn * 64 + (lane & 15);
    float bias_v[4];
#pragma unroll
    for (int n = 0; n < 4; ++n) bias_v[n] = hbias[colbase + n * 16];

    if (!FUSE_OUT) {
#pragma unroll
        for (int m = 0; m < 4; ++m) {
            int rbase = wm * 64 + m * 16 + ((lane >> 4) << 2);
#pragma unroll
            for (int n = 0; n < 4; ++n) {
#pragma unroll
                for (int q = 0; q < 4; ++q) {
                    float v = fmaxf(acc[m][n][q] + bias_v[n], 0.f);
                    float vo = __shfl_xor(v, 1);
                    if ((lane & 1) == 0) {
                        olds[(rbase + q) * 64 + wn * 32 + n * 8 + ((lane & 15) >> 1)] = pack2(v, vo);
                    }
                }
            }
        }
        __syncthreads();
#pragma unroll
        for (int i = 0; i < 8; ++i) {
            int j = i * 256 + tid;            // uint4 index over [128][16]
            int row = j >> 4, s = j & 15;
            int gr = m0 + row;
            if (gr < chunk_len) {
                ((uint4*)(hout + (size_t)(chunk_start + gr) * 64))[s] = ((const uint4*)olds)[j];
            }
        }
    } else {
        // write h1 to LDS with XOR swizzle (dword d ^= (row&7)<<2)
#pragma unroll
        for (int m = 0; m < 4; ++m) {
            int rbase = wm * 64 + m * 16 + ((lane >> 4) << 2);
#pragma unroll
            for (int n = 0; n < 4; ++n) {
#pragma unroll
                for (int q = 0; q < 4; ++q) {
                    float v = fmaxf(acc[m][n][q] + bias_v[n], 0.f);
                    float vo = __shfl_xor(v, 1);
                    if ((lane & 1) == 0) {
                        int row = rbase + q;
                        int d = wn * 32 + n * 8 + ((lane & 15) >> 1);
                        olds[row * 64 + (d ^ ((row & 7) << 2))] = pack2(v, vo);
                    }
                }
            }
        }
        __syncthreads();
        // mini-GEMM: out = relu(h1[128x128] @ WoutT^T[64x128] + bout), f32
        f32x4 acc2[4][2];
#pragma unroll
        for (int m = 0; m < 4; ++m)
#pragma unroll
            for (int n = 0; n < 2; ++n) acc2[m][n] = (f32x4)0.f;
#pragma unroll
        for (int ks = 0; ks < 4; ++ks) {
            int kb = ks * 64 + (lane >> 4) * 16;
            short8 a2[4], b2[2];
#pragma unroll
            for (int m = 0; m < 4; ++m) {
                int row = wm * 64 + m * 16 + (lane & 15);
                a2[m] = *(const short8*)((const char*)olds + row * 256 + (kb ^ ((row & 7) << 4)));
            }
#pragma unroll
            for (int n = 0; n < 2; ++n) {
                int col = wn * 32 + n * 16 + (lane & 15);
                b2[n] = *(const short8*)(Ws + col * 256 + (kb ^ ((col & 7) << 4)));
            }
#pragma unroll
            for (int m = 0; m < 4; ++m)
#pragma unroll
                for (int n = 0; n < 2; ++n)
                    acc2[m][n] = __builtin_amdgcn_mfma_f32_16x16x32_bf16(a2[m], b2[n], acc2[m][n], 0, 0, 0);
        }
        int colb = wn * 32 + (lane & 15);
        float bv2[2];
#pragma unroll
        for (int n = 0; n < 2; ++n) bv2[n] = bout[colb + n * 16];
#pragma unroll
        for (int m = 0; m < 4; ++m) {
            int rl0 = wm * 64 + m * 16 + ((lane >> 4) << 2);
#pragma unroll
            for (int n = 0; n < 2; ++n) {
#pragma unroll
                for (int q = 0; q < 4; ++q) {
                    int row = rl0 + q;
                    if (m0 + row < chunk_len) {
                        float v = fmaxf(acc2[m][n][q] + bv2[n], 0.f);
                        outp[(size_t)(chunk_start + m0 + row) * 64 + colb + n * 16] = v;
                    }
                }
            }
        }
    }
}

// ---------------- launch ----------------

static inline size_t align256(size_t x) { return (x + 255) & ~(size_t)255; }

extern "C" void kernel_launch(void* const* d_in, const int* in_sizes, int n_in,
                              void* d_out, int out_size, void* d_ws, size_t ws_size,
                              hipStream_t stream) {
    const float* feat   = (const float*)d_in[0];
    const float* win    = (const float*)d_in[1];
    const float* bin_   = (const float*)d_in[2];
    const float* basis0 = (const float*)d_in[3];
    const float* wcomp0 = (const float*)d_in[4];
    const float* loop0  = (const float*)d_in[5];
    const float* hbias0 = (const float*)d_in[6];
    const float* basis1 = (const float*)d_in[7];
    const float* wcomp1 = (const float*)d_in[8];
    const float* loop1  = (const float*)d_in[9];
    const float* hbias1 = (const float*)d_in[10];
    const float* wout   = (const float*)d_in[11];
    const float* bout   = (const float*)d_in[12];
    const int*   src    = (const int*)d_in[13];
    const int*   dst    = (const int*)d_in[14];
    const int*   etyp   = (const int*)d_in[15];
    float* outp = (float*)d_out;

    size_t off = 0;
    char* wsb = (char*)d_ws;
    auto walloc = [&](size_t bytes) { void* p = wsb + off; off += align256(bytes); return p; };
    unsigned* hA  = (unsigned*)walloc((size_t)NN * 64 * 4);     // 25.6 MB
    unsigned* hB  = (unsigned*)walloc((size_t)NN * 64 * 4);     // 25.6 MB
    int* offsets  = (int*)walloc((size_t)(NN + 1) * 4);
    int* counts   = (int*)walloc((size_t)NN * 4);
    int* totals   = (int*)walloc((size_t)NBLK * 4);
    int* gcursor  = (int*)walloc((size_t)NBUK * 4);
    int* packed   = (int*)walloc((size_t)(EE + 16) * 4);        // +pad for clamp overrun
    unsigned* tmp = (unsigned*)walloc((size_t)EE * 4);          // 6.4 MB
    unsigned short* BT0 = (unsigned short*)walloc((size_t)128 * 640 * 2);
    unsigned short* BT1 = (unsigned short*)walloc((size_t)128 * 640 * 2);
    unsigned short* winT = (unsigned short*)walloc((size_t)128 * 128 * 2);
    unsigned short* woutT = (unsigned short*)walloc((size_t)64 * 128 * 2);
    size_t fixed = off;

    int nchunk = 1;
    while (nchunk < 32) {
        size_t rows = (size_t)(NN + nchunk - 1) / nchunk;
        if (fixed + rows * 1024 <= ws_size) break;
        nchunk *= 2;
    }
    int chunk_rows = (NN + nchunk - 1) / nchunk;
    unsigned* tbuf = (unsigned*)(wsb + fixed);

    // CSR build
    hipMemsetAsync(counts, 0, (size_t)NN * 4, stream);
    count_kernel<<<(EE + 255) / 256, 256, 0, stream>>>(dst, counts);
    scan1<<<NBLK, 256, 0, stream>>>(counts, offsets, totals);
    scan2<<<1, 128, 0, stream>>>(totals, offsets, gcursor);
    scan3<<<(NN + 255) / 256, 256, 0, stream>>>(offsets, totals);
    bin_pass1<<<P1BLOCKS, 256, 0, stream>>>(src, dst, etyp, gcursor, tmp);
    bin_pass2<<<NBUK, 1024, 0, stream>>>(tmp, offsets, packed);

    // weight conversions
    convert_weights<<<(188416 + 255) / 256, 256, 0, stream>>>(
        basis0, loop0, basis1, loop1, win, wout, BT0, BT1, winT, woutT);

    int gblocks = (NN + 127) / 128;  // 782
    // input layer (MFMA, f32 A converted in staging)
    gemm128<128, false, true><<<gblocks, 256, 0, stream>>>(feat, winT, bin_, hA, NN);

    // conv layer 0: hA -> hB
    for (int s = 0; s < NN; s += chunk_rows) {
        int len = (NN - s < chunk_rows) ? (NN - s) : chunk_rows;
        int npairs = (len + 1) / 2;
        agg_kernel<<<(npairs + 3) / 4, 256, 0, stream>>>(hA, offsets, packed, wcomp0, tbuf, s, len);
        conv_gemm<false><<<(len + 127) / 128, 256, 0, stream>>>(
            tbuf, hA, BT0, hbias0, hB, nullptr, nullptr, nullptr, s, len);
    }
    // conv layer 1 + fused output layer: hB -> out
    for (int s = 0; s < NN; s += chunk_rows) {
        int len = (NN - s < chunk_rows) ? (NN - s) : chunk_rows;
        int npairs = (len + 1) / 2;
        agg_kernel<<<(npairs + 3) / 4, 256, 0, stream>>>(hB, offsets, packed, wcomp1, tbuf, s, len);
        conv_gemm<true><<<(len + 127) / 128, 256, 0, stream>>>(
            tbuf, hB, BT1, hbias1, nullptr, woutT, bout, outp, s, len);
    }
}